// Round 3
// baseline (10084.228 us; speedup 1.0000x reference)
//
#include <hip/hip_runtime.h>
#include <stdint.h>

// Baum-Welch forward-backward posteriors (log_gamma), MI355X gfx950.
//
// Design (defensive revision: no d_ws use, no exotic builtins):
//  - Linear-space recursions with exact per-step renormalization applied at
//    the consumer side of the dot (scale constants cancel in gamma's
//    per-(n,t) normalization, so fwd stores unnormalized alpha).
//  - 1 workgroup (256 threads = 4 waves) per sequence; 256 blocks = 1/CU.
//  - exp(log_A) register-resident: each thread holds a 64x4 fp32 quarter
//    (256 VGPRs; launch_bounds(256,1) allows 512). Inner product = plain
//    v_fmac_f32 against the LDS-staged per-step vector (broadcast reads).
//  - 2 __syncthreads per step. Emission read = direct gather lB[j*V+obs[t]],
//    issued before the dot so latency hides.
//  - fwd writes (arbitrary-scaled) alpha fp32 into d_out; bwd reads it and
//    overwrites with log_gamma in place. No scratch, no memset needed.

#define NB 256
#define TT 512
#define KK 256
#define VV 4096
#define LOG2E 1.44269504088896f
#define LN2 0.693147180559945f

// MODE 0: forward (writes scaled alpha). MODE 1: backward + fused gamma.
template <int MODE>
__global__ __launch_bounds__(256, 1) void hmm_recur(
    const float* __restrict__ lpi, const float* __restrict__ lA,
    const float* __restrict__ lB, const int* __restrict__ obs,
    float* __restrict__ gout) {
  const int n = blockIdx.x;
  const int tid = threadIdx.x;
  const int h = tid >> 6;  // wave id = quarter of the reduction axis
  const int c = tid & 63;  // lane id
  const int j = tid;       // state index in per-state phases

  __shared__ int obs_s[TT];
  __shared__ float avec[KK];     // staged per-step vector (alpha or w)
  __shared__ float part[4][KK];  // per-quarter partial sums
  __shared__ float redA[4];      // per-wave sums: staged-vector total
  __shared__ float redB[4];      // per-wave sums: gamma total (bwd)

  for (int i = tid; i < TT; i += 256) obs_s[i] = obs[n * TT + i];

  // Register-resident exp(A) quarter, fp32.
  // fwd: areg[q][m] = exp(A[h*64+m][c+64q])   (reduce over rows i)
  // bwd: areg[q][m] = exp(A[c+64q][h*64+m])   (reduce over cols j)
  float areg[4][64];
#pragma unroll 4
  for (int m = 0; m < 64; ++m) {
#pragma unroll
    for (int q = 0; q < 4; ++q) {
      size_t idx = (MODE == 0) ? ((size_t)(h * 64 + m) * KK + (c + 64 * q))
                               : ((size_t)(c + 64 * q) * KK + (h * 64 + m));
      areg[q][m] = exp2f(lA[idx] * LOG2E);
    }
  }
  __syncthreads();  // obs_s ready

  // p[q] = sum_{m in quarter h} avec[h*64+m] * areg[q][m]
  auto dot4 = [&](float p[4]) {
    float a0 = 0.f, a1 = 0.f, a2 = 0.f, a3 = 0.f;
    float b0 = 0.f, b1 = 0.f, b2 = 0.f, b3 = 0.f;
    const float* av = &avec[h * 64];
#pragma unroll
    for (int m = 0; m < 64; m += 2) {
      float x0 = av[m], x1 = av[m + 1];
      a0 += x0 * areg[0][m];
      a1 += x0 * areg[1][m];
      a2 += x0 * areg[2][m];
      a3 += x0 * areg[3][m];
      b0 += x1 * areg[0][m + 1];
      b1 += x1 * areg[1][m + 1];
      b2 += x1 * areg[2][m + 1];
      b3 += x1 * areg[3][m + 1];
    }
    p[0] = a0 + b0;
    p[1] = a1 + b1;
    p[2] = a2 + b2;
    p[3] = a3 + b3;
  };

  if (MODE == 0) {
    // ---- forward ----
    int o0 = obs_s[0];
    float u = exp2f((lpi[j] + lB[(size_t)j * VV + o0]) * LOG2E);
    avec[j] = u;
    gout[((size_t)n * TT + 0) * KK + j] = u;
    float S = u;
#pragma unroll
    for (int d = 1; d < 64; d <<= 1) S += __shfl_xor(S, d);
    if (c == 0) redA[h] = S;
    __syncthreads();  // avec + redA visible
    S = redA[0] + redA[1] + redA[2] + redA[3];

#pragma unroll 1
    for (int t = 1; t < TT; ++t) {
      int o = obs_s[t];
      float b = exp2f(lB[(size_t)j * VV + o] * LOG2E);  // issued pre-dot
      float p[4];
      dot4(p);
      part[h][c] = p[0];
      part[h][c + 64] = p[1];
      part[h][c + 128] = p[2];
      part[h][c + 192] = p[3];
      __syncthreads();  // barrier A: dot reads done, partials visible
      float colsum = part[0][j] + part[1][j] + part[2][j] + part[3][j];
      float u2 = colsum * (256.0f / S) * b;  // exact current-step normalizer
      avec[j] = u2;
      gout[((size_t)n * TT + t) * KK + j] = u2;
      float S2 = u2;
#pragma unroll
      for (int d = 1; d < 64; d <<= 1) S2 += __shfl_xor(S2, d);
      if (c == 0) redA[h] = S2;
      __syncthreads();  // barrier B: avec + redA visible
      S = redA[0] + redA[1] + redA[2] + redA[3];
    }
  } else {
    // ---- backward + fused gamma (in place over alpha) ----
    int oT = obs_s[TT - 1];
    size_t rowT = ((size_t)n * TT + (TT - 1)) * KK + j;
    float av = gout[rowT];  // alpha_{T-1} (arbitrary per-t scale; cancels)
    float bT = exp2f(lB[(size_t)j * VV + oT] * LOG2E);
    float u = bT;  // staged w = b_{T-1} * beta_{T-1}(=1)
    avec[j] = u;
    float S2 = u, g2 = av;  // gamma_{T-1} ∝ alpha (beta=1)
#pragma unroll
    for (int d = 1; d < 64; d <<= 1) {
      S2 += __shfl_xor(S2, d);
      g2 += __shfl_xor(g2, d);
    }
    if (c == 0) {
      redA[h] = S2;
      redB[h] = g2;
    }
    __syncthreads();
    float S = redA[0] + redA[1] + redA[2] + redA[3];
    float s2 = redB[0] + redB[1] + redB[2] + redB[3];
    gout[rowT] = (log2f(av) - log2f(s2)) * LN2;

#pragma unroll 1
    for (int t = TT - 2; t >= 0; --t) {
      int o = obs_s[t];
      float b = exp2f(lB[(size_t)j * VV + o] * LOG2E);  // b_t, pre-dot
      size_t row = ((size_t)n * TT + t) * KK + j;
      float av2 = gout[row];  // alpha_t, latency hidden under dot
      float p[4];
      dot4(p);
      part[h][c] = p[0];
      part[h][c + 64] = p[1];
      part[h][c + 128] = p[2];
      part[h][c + 192] = p[3];
      __syncthreads();  // barrier A
      float bu = (part[0][j] + part[1][j] + part[2][j] + part[3][j]) *
                 (256.0f / S);    // beta_t, O(1) scale
      float gg = av2 * bu;        // ∝ gamma numerator
      float u2 = bu * b;          // next staged w
      avec[j] = u2;
      float s1 = u2, sg = gg;
#pragma unroll
      for (int d = 1; d < 64; d <<= 1) {
        s1 += __shfl_xor(s1, d);
        sg += __shfl_xor(sg, d);
      }
      if (c == 0) {
        redA[h] = s1;
        redB[h] = sg;
      }
      __syncthreads();  // barrier B
      S = redA[0] + redA[1] + redA[2] + redA[3];
      s2 = redB[0] + redB[1] + redB[2] + redB[3];
      gout[row] = (log2f(gg) - log2f(s2)) * LN2;  // exact log_gamma
    }
  }
}

extern "C" void kernel_launch(void* const* d_in, const int* in_sizes, int n_in,
                              void* d_out, int out_size, void* d_ws, size_t ws_size,
                              hipStream_t stream) {
  const float* lpi = (const float*)d_in[0];
  const float* lA = (const float*)d_in[1];
  const float* lB = (const float*)d_in[2];
  const int* obs = (const int*)d_in[3];
  float* gout = (float*)d_out;
  (void)d_ws; (void)ws_size;  // deliberately unused (unknown size)

  hmm_recur<0><<<NB, 256, 0, stream>>>(lpi, lA, lB, obs, gout);
  hmm_recur<1><<<NB, 256, 0, stream>>>(lpi, lA, lB, obs, gout);
}

// Round 4
// 2260.017 us; speedup vs baseline: 4.4620x; 4.4620x over previous
//
#include <hip/hip_runtime.h>
#include <stdint.h>

// Baum-Welch forward-backward posteriors (log_gamma), MI355X gfx950.
//
// R3 -> R4 fix: the R3 kernel's areg[4][64] was NOT register-allocated
// (VGPR_Count=32): the partially-unrolled init loop left a dynamic index,
// SROA failed, and the transition matrix spilled to scratch -> 19 GB of HBM
// traffic per dispatch, VALUBusy 5%. This version fully unrolls every loop
// that touches areg (all indices compile-time constants) so exp(log_A) is
// truly register-resident (~256 VGPRs; 1 wave/SIMD so the 512 limit is free),
// and vectorizes the staged-vector LDS reads to float4.
//
// Design:
//  - Linear-space recursions, exact per-step renormalization at the consumer
//    side (scales cancel in gamma's per-(n,t) normalization).
//  - 1 workgroup (256 thr = 4 waves) per sequence; fwd then bwd kernel.
//  - 2 __syncthreads per step; partial sums exchanged through LDS.
//  - fwd writes scaled alpha fp32 to d_out; bwd overwrites with log_gamma.
//  - d_ws deliberately unused.

#define NB 256
#define TT 512
#define KK 256
#define VV 4096
#define LOG2E 1.44269504088896f
#define LN2 0.693147180559945f

struct alignas(16) F4 { float x, y, z, w; };

// MODE 0: forward (writes scaled alpha). MODE 1: backward + fused gamma.
template <int MODE>
__global__ __launch_bounds__(256, 1) void hmm_recur(
    const float* __restrict__ lpi, const float* __restrict__ lA,
    const float* __restrict__ lB, const int* __restrict__ obs,
    float* __restrict__ gout) {
  const int n = blockIdx.x;
  const int tid = threadIdx.x;
  const int h = tid >> 6;  // wave id = quarter of the reduction axis
  const int c = tid & 63;  // lane id
  const int j = tid;       // state index in per-state phases

  __shared__ int obs_s[TT];
  __shared__ F4 avec4[KK / 4];   // staged per-step vector (alpha or w)
  __shared__ float part[4][KK];  // per-quarter partial sums
  __shared__ float redA[4];      // per-wave sums: staged-vector total
  __shared__ float redB[4];      // per-wave sums: gamma total (bwd)
  float* avec = reinterpret_cast<float*>(avec4);

  for (int i = tid; i < TT; i += 256) obs_s[i] = obs[n * TT + i];

  // Register-resident exp(A) quarter, fp32. ALL indices compile-time const.
  // fwd: areg[q][m] = exp(A[h*64+m][c+64q])   (reduce over rows i)
  // bwd: areg[q][m] = exp(A[c+64q][h*64+m])   (reduce over cols j)
  float areg[4][64];
#pragma unroll
  for (int m = 0; m < 64; ++m) {
#pragma unroll
    for (int q = 0; q < 4; ++q) {
      size_t idx = (MODE == 0) ? ((size_t)(h * 64 + m) * KK + (c + 64 * q))
                               : ((size_t)(c + 64 * q) * KK + (h * 64 + m));
      areg[q][m] = exp2f(lA[idx] * LOG2E);
    }
  }
  __syncthreads();  // obs_s ready

  // p[q] = sum_{m in quarter h} avec[h*64+m] * areg[q][m]
  // Fully unrolled; avec read as float4 broadcasts (ds_read_b128).
  auto dot4 = [&](float p[4]) {
    float a0 = 0.f, a1 = 0.f, a2 = 0.f, a3 = 0.f;
    float b0 = 0.f, b1 = 0.f, b2 = 0.f, b3 = 0.f;
    const F4* av = &avec4[h * 16];
#pragma unroll
    for (int m4 = 0; m4 < 16; ++m4) {
      F4 x = av[m4];
      a0 += x.x * areg[0][4 * m4 + 0];
      a1 += x.x * areg[1][4 * m4 + 0];
      a2 += x.x * areg[2][4 * m4 + 0];
      a3 += x.x * areg[3][4 * m4 + 0];
      b0 += x.y * areg[0][4 * m4 + 1];
      b1 += x.y * areg[1][4 * m4 + 1];
      b2 += x.y * areg[2][4 * m4 + 1];
      b3 += x.y * areg[3][4 * m4 + 1];
      a0 += x.z * areg[0][4 * m4 + 2];
      a1 += x.z * areg[1][4 * m4 + 2];
      a2 += x.z * areg[2][4 * m4 + 2];
      a3 += x.z * areg[3][4 * m4 + 2];
      b0 += x.w * areg[0][4 * m4 + 3];
      b1 += x.w * areg[1][4 * m4 + 3];
      b2 += x.w * areg[2][4 * m4 + 3];
      b3 += x.w * areg[3][4 * m4 + 3];
    }
    p[0] = a0 + b0;
    p[1] = a1 + b1;
    p[2] = a2 + b2;
    p[3] = a3 + b3;
  };

  if (MODE == 0) {
    // ---- forward ----
    int o0 = obs_s[0];
    float u = exp2f((lpi[j] + lB[(size_t)j * VV + o0]) * LOG2E);
    avec[j] = u;
    gout[((size_t)n * TT + 0) * KK + j] = u;
    float S = u;
#pragma unroll
    for (int d = 1; d < 64; d <<= 1) S += __shfl_xor(S, d);
    if (c == 0) redA[h] = S;
    __syncthreads();  // avec + redA visible
    S = redA[0] + redA[1] + redA[2] + redA[3];

#pragma unroll 1
    for (int t = 1; t < TT; ++t) {
      int o = obs_s[t];
      float b = exp2f(lB[(size_t)j * VV + o] * LOG2E);  // issued pre-dot
      float p[4];
      dot4(p);
      part[h][c] = p[0];
      part[h][c + 64] = p[1];
      part[h][c + 128] = p[2];
      part[h][c + 192] = p[3];
      __syncthreads();  // barrier A: dot reads done, partials visible
      float colsum = part[0][j] + part[1][j] + part[2][j] + part[3][j];
      float u2 = colsum * (256.0f / S) * b;  // exact current-step normalizer
      avec[j] = u2;
      gout[((size_t)n * TT + t) * KK + j] = u2;
      float S2 = u2;
#pragma unroll
      for (int d = 1; d < 64; d <<= 1) S2 += __shfl_xor(S2, d);
      if (c == 0) redA[h] = S2;
      __syncthreads();  // barrier B: avec + redA visible
      S = redA[0] + redA[1] + redA[2] + redA[3];
    }
  } else {
    // ---- backward + fused gamma (in place over alpha) ----
    int oT = obs_s[TT - 1];
    size_t rowT = ((size_t)n * TT + (TT - 1)) * KK + j;
    float av = gout[rowT];  // alpha_{T-1} (arbitrary per-t scale; cancels)
    float bT = exp2f(lB[(size_t)j * VV + oT] * LOG2E);
    float u = bT;  // staged w = b_{T-1} * beta_{T-1}(=1)
    avec[j] = u;
    float S2 = u, g2 = av;  // gamma_{T-1} ∝ alpha (beta=1)
#pragma unroll
    for (int d = 1; d < 64; d <<= 1) {
      S2 += __shfl_xor(S2, d);
      g2 += __shfl_xor(g2, d);
    }
    if (c == 0) {
      redA[h] = S2;
      redB[h] = g2;
    }
    __syncthreads();
    float S = redA[0] + redA[1] + redA[2] + redA[3];
    float s2 = redB[0] + redB[1] + redB[2] + redB[3];
    gout[rowT] = (log2f(av) - log2f(s2)) * LN2;

#pragma unroll 1
    for (int t = TT - 2; t >= 0; --t) {
      int o = obs_s[t];
      float b = exp2f(lB[(size_t)j * VV + o] * LOG2E);  // b_t, pre-dot
      size_t row = ((size_t)n * TT + t) * KK + j;
      float av2 = gout[row];  // alpha_t, latency hidden under dot
      float p[4];
      dot4(p);
      part[h][c] = p[0];
      part[h][c + 64] = p[1];
      part[h][c + 128] = p[2];
      part[h][c + 192] = p[3];
      __syncthreads();  // barrier A
      float bu = (part[0][j] + part[1][j] + part[2][j] + part[3][j]) *
                 (256.0f / S);    // beta_t, O(1) scale
      float gg = av2 * bu;        // ∝ gamma numerator
      float u2 = bu * b;          // next staged w
      avec[j] = u2;
      float s1 = u2, sg = gg;
#pragma unroll
      for (int d = 1; d < 64; d <<= 1) {
        s1 += __shfl_xor(s1, d);
        sg += __shfl_xor(sg, d);
      }
      if (c == 0) {
        redA[h] = s1;
        redB[h] = sg;
      }
      __syncthreads();  // barrier B
      S = redA[0] + redA[1] + redA[2] + redA[3];
      s2 = redB[0] + redB[1] + redB[2] + redB[3];
      gout[row] = (log2f(gg) - log2f(s2)) * LN2;  // exact log_gamma
    }
  }
}

extern "C" void kernel_launch(void* const* d_in, const int* in_sizes, int n_in,
                              void* d_out, int out_size, void* d_ws, size_t ws_size,
                              hipStream_t stream) {
  const float* lpi = (const float*)d_in[0];
  const float* lA = (const float*)d_in[1];
  const float* lB = (const float*)d_in[2];
  const int* obs = (const int*)d_in[3];
  float* gout = (float*)d_out;
  (void)d_ws; (void)ws_size;  // deliberately unused

  hmm_recur<0><<<NB, 256, 0, stream>>>(lpi, lA, lB, obs, gout);
  hmm_recur<1><<<NB, 256, 0, stream>>>(lpi, lA, lB, obs, gout);
}

// Round 5
// 985.625 us; speedup vs baseline: 10.2313x; 2.2930x over previous
//
#include <hip/hip_runtime.h>
#include <stdint.h>

// Baum-Welch forward-backward posteriors (log_gamma), MI355X gfx950.
//
// R4 -> R5: R4 was latency-bound (VALUBusy 25%, 5800 cyc/step, 1 wave/SIMD,
// grid-limited occupancy). This version:
//  - 512-thread blocks (8 waves = 2/SIMD): wave g reduces chunk [32g,32g+32),
//    areg = 128 VGPRs as float2 pairs -> v_pk_fma_f32 (2 FMA/lane/cy).
//  - No exact per-step normalizer: scale by rcp(colsum[state0]) (any
//    block-uniform scale cancels in gamma's per-(n,t) normalization).
//    Deletes shuffle-reduce + cross-wave scalar round-trip per step.
//  - bwd gamma denominator via one-step-DEFERRED LDS atomicAdd pipeline
//    (3-cell rotation), off the critical path; output stored one step late.
//  - fwd alpha buffered in LDS, flushed every 8 steps as float4 stores
//    (store drain at barriers amortized 8x).
//  - Emission gather + bwd alpha row prefetched at top of each iteration
//    (latency hidden under the dot).
//  - 2 __syncthreads per step. d_ws unused.

#define NB 256
#define TT 512
#define KK 256
#define VV 4096
#define LOG2E 1.44269504088896f
#define LN2 0.693147180559945f

typedef float f2 __attribute__((ext_vector_type(2)));
typedef float f4 __attribute__((ext_vector_type(4)));

// MODE 0: forward (writes scaled alpha). MODE 1: backward + fused gamma.
template <int MODE>
__global__ __launch_bounds__(512, 2) void hmm_recur(
    const float* __restrict__ lpi, const float* __restrict__ lA,
    const float* __restrict__ lB, const int* __restrict__ obs,
    float* __restrict__ gout) {
  const int n = blockIdx.x;
  const int tid = threadIdx.x;  // 0..511
  const int g = tid >> 6;       // wave id = eighth of the reduction axis
  const int c = tid & 63;       // lane id
  const int j = tid;            // state index (phase-2 active when j<KK)

  __shared__ int obs_s[TT];      // 2 KB
  __shared__ f4 avec4[KK / 4];   // 1 KB staged per-step vector
  __shared__ float part[8][KK];  // 8 KB per-wave partial sums
  __shared__ float abuf[8][KK];  // 8 KB alpha row buffer (fwd)
  __shared__ float sacc[4];      // bwd gamma-sum cells (3-cell rotation)
  float* avec = reinterpret_cast<float*>(avec4);

  for (int i = tid; i < TT; i += 512) obs_s[i] = obs[n * TT + i];
  if (MODE == 1 && tid < 4) sacc[tid] = 0.f;
  __syncthreads();  // obs_s + sacc ready

  // Register-resident exp(A): wave g, reduction chunk m in [32g, 32g+32).
  // fwd: apair[q][k] = ( expA[32g+2k][c+64q], expA[32g+2k+1][c+64q] )
  // bwd: apair[q][k] = ( expA[c+64q][32g+2k], expA[c+64q][32g+2k+1] )
  f2 apair[4][16];
  {
    const int base = g * 32;
#pragma unroll
    for (int k = 0; k < 16; ++k) {
#pragma unroll
      for (int q = 0; q < 4; ++q) {
        const int col = c + 64 * q;
        float e0, e1;
        if (MODE == 0) {
          e0 = lA[(size_t)(base + 2 * k) * KK + col];
          e1 = lA[(size_t)(base + 2 * k + 1) * KK + col];
        } else {
          e0 = lA[(size_t)col * KK + base + 2 * k];
          e1 = lA[(size_t)col * KK + base + 2 * k + 1];
        }
        f2 p;
        p[0] = exp2f(e0 * LOG2E);
        p[1] = exp2f(e1 * LOG2E);
        apair[q][k] = p;
      }
    }
  }

  // p[q] = sum over this wave's 32-chunk of avec * A-column(c+64q).
  // float2 accumulate -> v_pk_fma_f32; b128 broadcast LDS reads.
  auto dot4 = [&](float p[4]) {
    f2 acc0[4], acc1[4];
#pragma unroll
    for (int q = 0; q < 4; ++q) { acc0[q] = (f2)0.f; acc1[q] = (f2)0.f; }
    const f4* av = &avec4[g * 8];
#pragma unroll
    for (int m4 = 0; m4 < 8; ++m4) {
      f4 x = av[m4];
      f2 x0; x0[0] = x[0]; x0[1] = x[1];
      f2 x1; x1[0] = x[2]; x1[1] = x[3];
#pragma unroll
      for (int q = 0; q < 4; ++q) {
        acc0[q] += x0 * apair[q][2 * m4];
        acc1[q] += x1 * apair[q][2 * m4 + 1];
      }
    }
#pragma unroll
    for (int q = 0; q < 4; ++q)
      p[q] = (acc0[q][0] + acc0[q][1]) + (acc1[q][0] + acc1[q][1]);
  };

  if (MODE == 0) {
    // ---- forward ----
    float bl = 0.f;  // prefetched raw lB for the next step
    if (j < KK) {
      const int o0 = obs_s[0];
      float u = exp2f((lpi[j] + lB[(size_t)j * VV + o0]) * LOG2E);
      avec[j] = u;
      abuf[0][j] = u;
      bl = lB[(size_t)j * VV + obs_s[1]];
    }
    __syncthreads();  // avec row 0 staged

#pragma unroll 1
    for (int t = 1; t < TT; ++t) {
      float blnext = 0.f;
      if (j < KK && t + 1 < TT) blnext = lB[(size_t)j * VV + obs_s[t + 1]];
      float p[4];
      dot4(p);
      part[g][c] = p[0];
      part[g][c + 64] = p[1];
      part[g][c + 128] = p[2];
      part[g][c + 192] = p[3];
      __syncthreads();  // barrier A: partials visible
      if (j < KK) {
        float cs = 0.f, cs0 = 0.f;
#pragma unroll
        for (int w = 0; w < 8; ++w) {
          cs += part[w][j];
          cs0 += part[w][0];  // broadcast; any uniform scale works
        }
        float b = exp2f(bl * LOG2E);
        float u2 = cs * __builtin_amdgcn_rcpf(cs0) * b;
        avec[j] = u2;
        abuf[t & 7][j] = u2;
        bl = blnext;
      }
      __syncthreads();  // barrier B: avec staged
      if ((t & 7) == 7) {
        // flush alpha rows t-7..t: 2048 floats, 1 float4 per thread
        f4 v = *(const f4*)&abuf[g][c * 4];
        *(f4*)&gout[((size_t)n * TT + (t - 7 + g)) * KK + c * 4] = v;
      }
    }
  } else {
    // ---- backward + fused gamma (deferred one step) ----
    float bl = 0.f, avp = 0.f;  // prefetch: raw lB and alpha row
    float ggreg = 0.f;          // deferred gamma numerator (register)
    size_t rowreg = 0;          // deferred output row base + j
    if (j < KK) {
      const int oT = obs_s[TT - 1];
      rowreg = ((size_t)n * TT + (TT - 1)) * KK + j;
      float av = gout[rowreg];  // alpha_{T-1} (beta=1)
      float w = exp2f(lB[(size_t)j * VV + oT] * LOG2E);
      avec[j] = w;
      ggreg = av;
      float s = av;
#pragma unroll
      for (int d = 1; d < 64; d <<= 1) s += __shfl_xor(s, d);
      if (c == 0) atomicAdd(&sacc[(TT - 1) % 3], s);
      avp = gout[((size_t)n * TT + (TT - 2)) * KK + j];
      bl = lB[(size_t)j * VV + obs_s[TT - 2]];
    }
    __syncthreads();  // avec + sacc adds visible

#pragma unroll 1
    for (int t = TT - 2; t >= 0; --t) {
      float avnext = 0.f, blnext = 0.f;
      if (j < KK && t > 0) {
        avnext = gout[((size_t)n * TT + (t - 1)) * KK + j];
        blnext = lB[(size_t)j * VV + obs_s[t - 1]];
      }
      float p[4];
      dot4(p);
      part[g][c] = p[0];
      part[g][c + 64] = p[1];
      part[g][c + 128] = p[2];
      part[g][c + 192] = p[3];
      __syncthreads();  // barrier A
      if (j < KK) {
        float cs = 0.f, cs0 = 0.f;
#pragma unroll
        for (int w = 0; w < 8; ++w) {
          cs += part[w][j];
          cs0 += part[w][0];
        }
        float bu = cs * __builtin_amdgcn_rcpf(cs0);  // beta_t (scaled)
        float b = exp2f(bl * LOG2E);
        avec[j] = bu * b;      // staged w_t for next dot
        float gg = avp * bu;   // gamma numerator, step t
        // emit deferred output for step t+1 (sum completed last barrier)
        float s2 = sacc[(t + 1) % 3];
        gout[rowreg] = (log2f(ggreg) - log2f(s2)) * LN2;
        if (tid == 0) sacc[(t + 2) % 3] = 0.f;  // recycle for step t-1
        float s = gg;
#pragma unroll
        for (int d = 1; d < 64; d <<= 1) s += __shfl_xor(s, d);
        if (c == 0) atomicAdd(&sacc[t % 3], s);
        ggreg = gg;
        rowreg = ((size_t)n * TT + t) * KK + j;
        avp = avnext;
        bl = blnext;
      }
      __syncthreads();  // barrier B
    }
    if (j < KK) {  // final deferred row (t=0)
      float s2 = sacc[0];
      gout[rowreg] = (log2f(ggreg) - log2f(s2)) * LN2;
    }
  }
}

extern "C" void kernel_launch(void* const* d_in, const int* in_sizes, int n_in,
                              void* d_out, int out_size, void* d_ws, size_t ws_size,
                              hipStream_t stream) {
  const float* lpi = (const float*)d_in[0];
  const float* lA = (const float*)d_in[1];
  const float* lB = (const float*)d_in[2];
  const int* obs = (const int*)d_in[3];
  float* gout = (float*)d_out;
  (void)d_ws; (void)ws_size;  // deliberately unused

  hmm_recur<0><<<NB, 512, 0, stream>>>(lpi, lA, lB, obs, gout);
  hmm_recur<1><<<NB, 512, 0, stream>>>(lpi, lA, lB, obs, gout);
}